// Round 2
// baseline (99.212 us; speedup 1.0000x reference)
//
#include <hip/hip_runtime.h>
#include <hip/hip_bf16.h>
#include <stdint.h>

#define HW 16384   // H*W
#define C 128

typedef __attribute__((ext_vector_type(8))) short bf16x8;
typedef __attribute__((ext_vector_type(4))) float f32x4;
typedef __attribute__((ext_vector_type(4))) unsigned short u16x4;

__device__ __forceinline__ uint16_t bf16_rne(float f) {
    uint32_t u = __builtin_bit_cast(uint32_t, f);
    u += 0x7FFFu + ((u >> 16) & 1u);
    return (uint16_t)(u >> 16);
}

// ---------------------------------------------------------------------------
// Kernel 1: pack gamma (f32 [128][128]) into bf16 MFMA A-fragment order.
// ws layout: ushort gfrag[8 ot][4 ks][64 lane][8 j]
//   element = gamma[o = 16*ot + (lane&15)][c = 32*ks + 8*(lane>>4) + j]
// ---------------------------------------------------------------------------
__global__ void gdn_prep_gamma(const float* __restrict__ gamma,
                               uint16_t* __restrict__ gws) {
    int t = blockIdx.x * 256 + threadIdx.x;   // 0..2047, one 16B frag-block each
    int l  = t & 63;
    int ks = (t >> 6) & 3;
    int ot = t >> 8;
    int o  = (ot << 4) | (l & 15);
    int c0 = (ks << 5) + ((l >> 4) << 3);
    const float* gp = gamma + o * C + c0;
    bf16x8 v;
#pragma unroll
    for (int j = 0; j < 8; ++j) v[j] = (short)bf16_rne(gp[j]);
    *reinterpret_cast<bf16x8*>(gws + (size_t)t * 8) = v;
}

// ---------------------------------------------------------------------------
// Main kernel: block = 128 consecutive pixels x all 128 channels.
// Phase A: coalesced float4 x-loads -> x^2 bf16 -> LDS [p][c] tile with
//          16B-slot XOR swizzle (slot ^= p&15)  -> conflict-light b128 reads.
// Phase B: B-frag = one ds_read_b128; A-frag streamed from global (L2-hot);
//          16x16x32 bf16 MFMA, beta folded into C-init.
// Epilogue: out = x * rsqrt(norm), x re-read (L1/L2-hot), scalar stores.
// ---------------------------------------------------------------------------
__global__ __launch_bounds__(256, 4)
void gdn_main(const float* __restrict__ x, const float* __restrict__ gamma,
              const float* __restrict__ beta, float* __restrict__ out,
              const uint16_t* __restrict__ gws) {
    __shared__ uint16_t x2t[128 * 128];   // 32 KB: [p][slot-swizzled c] bf16

    const int tid = threadIdx.x;
    const int b       = blockIdx.x >> 7;             // image
    const int pixBase = (blockIdx.x & 127) * 128;    // tile's first pixel
    const float* xb = x   + (size_t)b * C * HW;
    float*       ob = out + (size_t)b * C * HW;

    // ---- Phase A: load tile, square, transpose into LDS ----
    {
        const int pq = tid & 31;          // pixel quad: pixels 4*pq..4*pq+3
        const int cb = tid >> 5;          // 0..7 -> channel sub-block
        const int p0 = pq * 4;
#pragma unroll
        for (int g = 0; g < 4; ++g) {
            const int c0 = g * 32 + cb * 4;
            f32x4 v[4];
#pragma unroll
            for (int r = 0; r < 4; ++r)
                v[r] = *reinterpret_cast<const f32x4*>(
                    xb + (size_t)(c0 + r) * HW + pixBase + p0);
            const int slot = g * 4 + (cb >> 1);
#pragma unroll
            for (int e = 0; e < 4; ++e) {
                const int p = p0 + e;
                u16x4 wv;
#pragma unroll
                for (int r = 0; r < 4; ++r)
                    wv[r] = bf16_rne(v[r][e] * v[r][e]);
                const int sl = slot ^ (p & 15);
                // byte addr = p*256 + sl*16 + (cb&1)*8 ; index in u16 units:
                *reinterpret_cast<u16x4*>(&x2t[p * 128 + sl * 8 + (cb & 1) * 4]) = wv;
            }
        }
    }
    __syncthreads();

    const int lane = tid & 63;
    const int w    = tid >> 6;
    const int lp = lane & 15;   // pixel within strip (MFMA col)
    const int lg = lane >> 4;   // lane group 0..3
    const int pl0 = w * 32;     // wave's block-local pixel base

    // ---- acc init = beta (folded into MFMA C-input) ----
    f32x4 acc[2][8];
#pragma unroll
    for (int ot = 0; ot < 8; ++ot) {
        f32x4 bv = *reinterpret_cast<const f32x4*>(beta + ot * 16 + lg * 4);
        acc[0][ot] = bv;
        acc[1][ot] = bv;
    }

    // ---- MFMA: norm[o][p] = gamma @ xsq + beta ----
    if (gws) {
#pragma unroll
        for (int ks = 0; ks < 4; ++ks) {
            bf16x8 b0, b1;
            {
                const int p0l = pl0 + lp;
                const int sl0 = ((ks * 4 + lg) ^ (p0l & 15));
                b0 = *reinterpret_cast<const bf16x8*>(&x2t[p0l * 128 + sl0 * 8]);
                const int p1l = pl0 + 16 + lp;
                const int sl1 = ((ks * 4 + lg) ^ (p1l & 15));
                b1 = *reinterpret_cast<const bf16x8*>(&x2t[p1l * 128 + sl1 * 8]);
            }
#pragma unroll
            for (int ot = 0; ot < 8; ++ot) {
                bf16x8 a = *reinterpret_cast<const bf16x8*>(
                    gws + ((size_t)(ot * 4 + ks) * 64 + lane) * 8);
                acc[0][ot] = __builtin_amdgcn_mfma_f32_16x16x32_bf16(a, b0, acc[0][ot], 0, 0, 0);
                acc[1][ot] = __builtin_amdgcn_mfma_f32_16x16x32_bf16(a, b1, acc[1][ot], 0, 0, 0);
            }
        }
    } else {
        // fallback: build A-frags from fp32 gamma (L2-resident), slower
#pragma unroll
        for (int ks = 0; ks < 4; ++ks) {
            bf16x8 b0, b1;
            {
                const int p0l = pl0 + lp;
                const int sl0 = ((ks * 4 + lg) ^ (p0l & 15));
                b0 = *reinterpret_cast<const bf16x8*>(&x2t[p0l * 128 + sl0 * 8]);
                const int p1l = pl0 + 16 + lp;
                const int sl1 = ((ks * 4 + lg) ^ (p1l & 15));
                b1 = *reinterpret_cast<const bf16x8*>(&x2t[p1l * 128 + sl1 * 8]);
            }
#pragma unroll
            for (int ot = 0; ot < 8; ++ot) {
                const float* gp = gamma + (ot * 16 + lp) * C + ks * 32 + lg * 8;
                bf16x8 a;
#pragma unroll
                for (int j = 0; j < 8; ++j) a[j] = (short)bf16_rne(gp[j]);
                acc[0][ot] = __builtin_amdgcn_mfma_f32_16x16x32_bf16(a, b0, acc[0][ot], 0, 0, 0);
                acc[1][ot] = __builtin_amdgcn_mfma_f32_16x16x32_bf16(a, b1, acc[1][ot], 0, 0, 0);
            }
        }
    }

    // ---- epilogue: out = x * rsqrt(norm); x re-read is L1/L2-hot ----
#pragma unroll
    for (int s = 0; s < 2; ++s) {
        const int p = pixBase + pl0 + s * 16 + lp;
#pragma unroll
        for (int ot = 0; ot < 8; ++ot) {
            const int o0 = ot * 16 + lg * 4;
#pragma unroll
            for (int r = 0; r < 4; ++r) {
                float xv = xb[(size_t)(o0 + r) * HW + p];
                ob[(size_t)(o0 + r) * HW + p] = xv * rsqrtf(acc[s][ot][r]);
            }
        }
    }
}

extern "C" void kernel_launch(void* const* d_in, const int* in_sizes, int n_in,
                              void* d_out, int out_size, void* d_ws, size_t ws_size,
                              hipStream_t stream) {
    const float* x     = (const float*)d_in[0];
    const float* gamma = (const float*)d_in[1];
    const float* beta  = (const float*)d_in[2];
    float* out = (float*)d_out;

    uint16_t* gws = (d_ws && ws_size >= 32768) ? (uint16_t*)d_ws : nullptr;
    if (gws) {
        gdn_prep_gamma<<<8, 256, 0, stream>>>(gamma, gws);
    }
    // 16 images * 128 blocks/image = 2048 blocks
    gdn_main<<<2048, 256, 0, stream>>>(x, gamma, beta, out, gws);
}

// Round 3
// 66.505 us; speedup vs baseline: 1.4918x; 1.4918x over previous
//
#include <hip/hip_runtime.h>
#include <stdint.h>

#define HW 16384   // H*W
#define C 128

typedef __attribute__((ext_vector_type(8))) short bf16x8;
typedef __attribute__((ext_vector_type(8))) unsigned short u16x8;
typedef __attribute__((ext_vector_type(4))) float f32x4;

__device__ __forceinline__ uint16_t bf16_rne(float f) {
    uint32_t u = __builtin_bit_cast(uint32_t, f);
    u += 0x7FFFu + ((u >> 16) & 1u);
    return (uint16_t)(u >> 16);
}

// ---------------------------------------------------------------------------
// Kernel 1: pack gamma (f32 [128][128]) into bf16 MFMA B-fragment order.
// ws layout: ushort gfrag[8 ot][4 ks][64 lane][8 j]
//   element = gamma[o = 16*ot + (lane&15)][c = 32*ks + 8*(lane>>4) + j]
// (B[k=c][col=o] = gamma[o][c]; same packing as the old A-role.)
// ---------------------------------------------------------------------------
__global__ void gdn_prep_gamma(const float* __restrict__ gamma,
                               uint16_t* __restrict__ gws) {
    int t = blockIdx.x * 256 + threadIdx.x;   // 0..2047
    int l  = t & 63;
    int ks = (t >> 6) & 3;
    int ot = t >> 8;
    int o  = (ot << 4) | (l & 15);
    int c0 = (ks << 5) + ((l >> 4) << 3);
    const float* gp = gamma + o * C + c0;
    u16x8 v;
#pragma unroll
    for (int j = 0; j < 8; ++j) v[j] = bf16_rne(gp[j]);
    *reinterpret_cast<u16x8*>(gws + (size_t)t * 8) = v;
}

// ---------------------------------------------------------------------------
// Main kernel: block = 128 pixels x 128 channels, 512 threads (8 waves).
// MFMA computes D[p][o] = x2[p][:] . gammaT[:][o] + beta[o]:
//   A = x^2 (from LDS transpose tile), B = gamma frags (LDS), so each lane
//   ends with 4 CONSECUTIVE PIXELS of one channel -> float4 epilogue.
// LDS swizzle sl = c_octet ^ (((p>>2)&3)<<1): 8 balanced bank-groups on both
// the transpose writes (entropy: lane pq bits) and frag reads (lp bits 2-3).
// ---------------------------------------------------------------------------
__global__ __launch_bounds__(512, 4)
void gdn_main(const float* __restrict__ x, const float* __restrict__ gamma,
              const float* __restrict__ beta, float* __restrict__ out,
              const uint16_t* __restrict__ gws) {
    __shared__ uint16_t x2t[128 * 128];    // 32 KB: [p][swizzled c-octet]
    __shared__ uint16_t gfrag[2048 * 8];   // 32 KB: linear frag order

    const int tid = threadIdx.x;
    const int b       = blockIdx.x >> 7;
    const int pixBase = (blockIdx.x & 127) * 128;
    const float* xb = x   + (size_t)b * C * HW;
    float*       ob = out + (size_t)b * C * HW;

    // ---- stage gamma fragments into LDS (linear, conflict-free) ----
    if (gws) {
#pragma unroll
        for (int j = 0; j < 4; ++j) {
            const int idx = tid + j * 512;
            *reinterpret_cast<u16x8*>(&gfrag[idx * 8]) =
                *reinterpret_cast<const u16x8*>(gws + (size_t)idx * 8);
        }
    } else {
        // fallback: build frags from fp32 gamma (L2-resident)
#pragma unroll
        for (int j = 0; j < 4; ++j) {
            const int idx = tid + j * 512;
            const int l = idx & 63, ks = (idx >> 6) & 3, ot = idx >> 8;
            const int o = ot * 16 + (l & 15), c0 = ks * 32 + (l >> 4) * 8;
            const float* gp = gamma + o * C + c0;
            u16x8 v;
#pragma unroll
            for (int q = 0; q < 8; ++q) v[q] = bf16_rne(gp[q]);
            *reinterpret_cast<u16x8*>(&gfrag[idx * 8]) = v;
        }
    }

    // ---- Phase A: coalesced x loads -> square -> bf16 -> swizzled LDS ----
    {
        const int pq  = tid & 31;          // pixel quad: pixels 4*pq..4*pq+3
        const int cb  = (tid >> 5) & 7;
        const int ih  = tid >> 8;          // channel half
        const int c0  = ih * 64 + cb * 8;  // 8 channels per thread
        const int lin = ih * 8 + cb;       // channel-octet slot
        const float* xp = xb + (size_t)c0 * HW + pixBase + pq * 4;
        f32x4 v[8];
#pragma unroll
        for (int r = 0; r < 8; ++r)
            v[r] = *reinterpret_cast<const f32x4*>(xp + (size_t)r * HW);
#pragma unroll
        for (int e = 0; e < 4; ++e) {
            const int p  = pq * 4 + e;
            const int sl = lin ^ (((p >> 2) & 3) << 1);
            u16x8 wv;
#pragma unroll
            for (int r = 0; r < 8; ++r) wv[r] = bf16_rne(v[r][e] * v[r][e]);
            *reinterpret_cast<u16x8*>(&x2t[p * 128 + sl * 8]) = wv;
        }
    }
    __syncthreads();

    const int lane = tid & 63;
    const int w    = tid >> 6;    // wave = pixel strip (16 pixels)
    const int lp   = lane & 15;
    const int lg   = lane >> 4;

    // ---- acc init = beta[o] (folded into MFMA C-input; rows are pixels) ----
    f32x4 acc[8];
#pragma unroll
    for (int ot = 0; ot < 8; ++ot) {
        const float bv = beta[ot * 16 + lp];
        acc[ot][0] = bv; acc[ot][1] = bv; acc[ot][2] = bv; acc[ot][3] = bv;
    }

    // ---- MFMA: D[p][o] = x2 @ gammaT + beta ----
#pragma unroll
    for (int ks = 0; ks < 4; ++ks) {
        const int p  = w * 16 + lp;                    // A row = pixel
        const int sl = (ks * 4 + lg) ^ (((p >> 2) & 3) << 1);
        const bf16x8 a = *reinterpret_cast<const bf16x8*>(&x2t[p * 128 + sl * 8]);
#pragma unroll
        for (int ot = 0; ot < 8; ++ot) {
            const bf16x8 bg = *reinterpret_cast<const bf16x8*>(
                &gfrag[((ot * 4 + ks) * 64 + lane) * 8]);
            acc[ot] = __builtin_amdgcn_mfma_f32_16x16x32_bf16(a, bg, acc[ot], 0, 0, 0);
        }
    }

    // ---- epilogue: lane holds 4 consecutive pixels of channel o ----
    const int pp = pixBase + w * 16 + lg * 4;
#pragma unroll
    for (int ot = 0; ot < 8; ++ot) {
        const int o = ot * 16 + lp;
        const f32x4 xv = *reinterpret_cast<const f32x4*>(xb + (size_t)o * HW + pp);
        f32x4 ov;
#pragma unroll
        for (int r = 0; r < 4; ++r) ov[r] = xv[r] * rsqrtf(acc[ot][r]);
        *reinterpret_cast<f32x4*>(ob + (size_t)o * HW + pp) = ov;
    }
}

extern "C" void kernel_launch(void* const* d_in, const int* in_sizes, int n_in,
                              void* d_out, int out_size, void* d_ws, size_t ws_size,
                              hipStream_t stream) {
    const float* x     = (const float*)d_in[0];
    const float* gamma = (const float*)d_in[1];
    const float* beta  = (const float*)d_in[2];
    float* out = (float*)d_out;

    uint16_t* gws = (d_ws && ws_size >= 32768) ? (uint16_t*)d_ws : nullptr;
    if (gws) {
        gdn_prep_gamma<<<8, 256, 0, stream>>>(gamma, gws);
    }
    // 16 images * 128 tiles/image = 2048 blocks, 512 threads each
    gdn_main<<<2048, 512, 0, stream>>>(x, gamma, beta, out, gws);
}

// Round 4
// 61.071 us; speedup vs baseline: 1.6245x; 1.0890x over previous
//
#include <hip/hip_runtime.h>
#include <stdint.h>

#define HW 16384   // H*W
#define C 128

typedef __attribute__((ext_vector_type(8))) short bf16x8;
typedef __attribute__((ext_vector_type(8))) unsigned short u16x8;
typedef __attribute__((ext_vector_type(4))) float f32x4;

__device__ __forceinline__ uint16_t bf16_rne(float f) {
    uint32_t u = __builtin_bit_cast(uint32_t, f);
    u += 0x7FFFu + ((u >> 16) & 1u);
    return (uint16_t)(u >> 16);
}

// ---------------------------------------------------------------------------
// Kernel 1: pack gamma into bf16 MFMA B-fragment order with the COLUMN
// PERMUTATION o = col*8 + ot (so MFMA #ot gives lane lp channel lp*8+ot ->
// each lane's 8 output channels are contiguous -> register-resident epilogue).
// ws layout: ushort gfrag[8 ot][4 ks][64 lane][8 j]
//   element = gamma[o = (lane&15)*8 + ot][c = ks*32 + (lane>>4)*8 + j]
// ---------------------------------------------------------------------------
__global__ void gdn_prep_gamma(const float* __restrict__ gamma,
                               uint16_t* __restrict__ gws) {
    int t = blockIdx.x * 256 + threadIdx.x;   // 0..2047
    int l  = t & 63;
    int ks = (t >> 6) & 3;
    int ot = t >> 8;
    int o  = ((l & 15) << 3) | ot;
    int c0 = (ks << 5) + ((l >> 4) << 3);
    const float* gp = gamma + o * C + c0;
    u16x8 v;
#pragma unroll
    for (int j = 0; j < 8; ++j) v[j] = bf16_rne(gp[j]);
    *reinterpret_cast<u16x8*>(gws + (size_t)t * 8) = v;
}

// ---------------------------------------------------------------------------
// Main kernel: block = 128 pixels x 128 channels, 512 threads (8 waves).
// Thread (w,lg,lp) owns pixels [w*16+lg*4 .. +3] x channels [lp*8 .. +7]:
//   - loads them as 8 float4 (fully coalesced, 64B segments)
//   - squares -> bf16 -> ONE u16x8 LDS write per pixel, slot = lp ^ (p&7)
//     (8 distinct 16B slots/instr, 8 lanes/slot distinct rows = b128 floor)
//   - MFMA A-read slot = (ks*4+lg) ^ (p&7), same floor property
//   - D[p][o]: lane lp, MFMA #ot -> channel lp*8+ot, rows = its own 4 pixels
//   - epilogue multiplies the REGISTER-held x by rsqrt(acc): no re-read.
// ---------------------------------------------------------------------------
__global__ __launch_bounds__(512, 4)
void gdn_main(const float* __restrict__ x, const float* __restrict__ gamma,
              const float* __restrict__ beta, float* __restrict__ out,
              const uint16_t* __restrict__ gws) {
    __shared__ uint16_t x2t[128 * 128];    // 32 KB: [p][swizzled c-octet]
    __shared__ uint16_t gfrag[2048 * 8];   // 32 KB: linear frag order

    const int tid = threadIdx.x;
    const int b       = blockIdx.x >> 7;
    const int pixBase = (blockIdx.x & 127) * 128;
    const float* xb = x   + (size_t)b * C * HW;
    float*       ob = out + (size_t)b * C * HW;

    // ---- stage gamma fragments into LDS (linear, conflict-free) ----
    if (gws) {
#pragma unroll
        for (int j = 0; j < 4; ++j) {
            const int idx = tid + j * 512;
            *reinterpret_cast<u16x8*>(&gfrag[idx * 8]) =
                *reinterpret_cast<const u16x8*>(gws + (size_t)idx * 8);
        }
    } else {
        // fallback: build frags from fp32 gamma (L2-resident)
#pragma unroll
        for (int j = 0; j < 4; ++j) {
            const int idx = tid + j * 512;
            const int l = idx & 63, ks = (idx >> 6) & 3, ot = idx >> 8;
            const int o = ((l & 15) << 3) | ot, c0 = ks * 32 + (l >> 4) * 8;
            const float* gp = gamma + o * C + c0;
            u16x8 v;
#pragma unroll
            for (int q = 0; q < 8; ++q) v[q] = bf16_rne(gp[q]);
            *reinterpret_cast<u16x8*>(&gfrag[idx * 8]) = v;
        }
    }

    const int lane = tid & 63;
    const int w    = tid >> 6;     // wave = 16-pixel strip
    const int lp   = lane & 15;
    const int lg   = lane >> 4;

    // ---- Phase A: coalesced loads, square, one b128 LDS write per pixel ----
    f32x4 xv[8];   // x[lp*8+j][myPix .. +3]  — kept live through epilogue
    {
        const float* xp = xb + (size_t)(lp * 8) * HW + pixBase + w * 16 + lg * 4;
#pragma unroll
        for (int j = 0; j < 8; ++j)
            xv[j] = *reinterpret_cast<const f32x4*>(xp + (size_t)j * HW);
#pragma unroll
        for (int e = 0; e < 4; ++e) {
            const int p = w * 16 + lg * 4 + e;       // block-local pixel
            u16x8 wv;
#pragma unroll
            for (int j = 0; j < 8; ++j) wv[j] = bf16_rne(xv[j][e] * xv[j][e]);
            const int slot = lp ^ (p & 7);
            *reinterpret_cast<u16x8*>(&x2t[p * 128 + slot * 8]) = wv;
        }
    }
    __syncthreads();

    // ---- acc init = beta[o = lp*8+ot] (folded into MFMA C-input) ----
    f32x4 acc[8];
    {
        const f32x4 b0 = *reinterpret_cast<const f32x4*>(beta + lp * 8);
        const f32x4 b1 = *reinterpret_cast<const f32x4*>(beta + lp * 8 + 4);
#pragma unroll
        for (int ot = 0; ot < 8; ++ot) {
            const float bv = (ot < 4) ? b0[ot & 3] : b1[ot & 3];
            acc[ot][0] = bv; acc[ot][1] = bv; acc[ot][2] = bv; acc[ot][3] = bv;
        }
    }

    // ---- MFMA: D[p][o] = x2 @ gammaT + beta ----
#pragma unroll
    for (int ks = 0; ks < 4; ++ks) {
        const int p    = w * 16 + lp;                 // A row = pixel
        const int slot = (ks * 4 + lg) ^ (p & 7);
        const bf16x8 a = *reinterpret_cast<const bf16x8*>(&x2t[p * 128 + slot * 8]);
#pragma unroll
        for (int ot = 0; ot < 8; ++ot) {
            const bf16x8 g = *reinterpret_cast<const bf16x8*>(
                &gfrag[((ot * 4 + ks) * 64 + lane) * 8]);
            acc[ot] = __builtin_amdgcn_mfma_f32_16x16x32_bf16(a, g, acc[ot], 0, 0, 0);
        }
    }

    // ---- epilogue: out = x * rsqrt(norm), x from registers ----
    float* op = ob + (size_t)(lp * 8) * HW + pixBase + w * 16 + lg * 4;
#pragma unroll
    for (int ot = 0; ot < 8; ++ot) {
        f32x4 ov;
#pragma unroll
        for (int r = 0; r < 4; ++r) ov[r] = xv[ot][r] * rsqrtf(acc[ot][r]);
        *reinterpret_cast<f32x4*>(op + (size_t)ot * HW) = ov;
    }
}

extern "C" void kernel_launch(void* const* d_in, const int* in_sizes, int n_in,
                              void* d_out, int out_size, void* d_ws, size_t ws_size,
                              hipStream_t stream) {
    const float* x     = (const float*)d_in[0];
    const float* gamma = (const float*)d_in[1];
    const float* beta  = (const float*)d_in[2];
    float* out = (float*)d_out;

    uint16_t* gws = (d_ws && ws_size >= 32768) ? (uint16_t*)d_ws : nullptr;
    if (gws) {
        gdn_prep_gamma<<<8, 256, 0, stream>>>(gamma, gws);
    }
    // 16 images * 128 tiles/image = 2048 blocks, 512 threads each
    gdn_main<<<2048, 512, 0, stream>>>(x, gamma, beta, out, gws);
}